// Round 1
// baseline (25032.874 us; speedup 1.0000x reference)
//
#include <hip/hip_runtime.h>
#include <math.h>

#define D 512
#define TSEQ 2048
#define NH 8
#define HD 64
#define NTOK 4096   // B*T
#define VOCAB 32000
#define NLAYER 6

__device__ __forceinline__ float wave_sum(float x) {
#pragma unroll
  for (int off = 32; off; off >>= 1) x += __shfl_xor(x, off, 64);
  return x;
}
__device__ __forceinline__ float wave_max(float x) {
#pragma unroll
  for (int off = 32; off; off >>= 1) x = fmaxf(x, __shfl_xor(x, off, 64));
  return x;
}

// x[n,d] = tok_emb[idx[n],d] + pos_emb[n % T, d]   (float4 granularity)
__global__ __launch_bounds__(256) void embed_kernel(
    const int* __restrict__ idx, const float* __restrict__ tok,
    const float* __restrict__ pos, float* __restrict__ x) {
  int i = blockIdx.x * 256 + threadIdx.x;      // float4 index, NTOK*D/4 total
  int n = i >> 7;                              // 128 float4 per row
  int c4 = (i & 127) << 2;
  int t = n & (TSEQ - 1);
  int tk = idx[n];
  float4 a = *(const float4*)(tok + (size_t)tk * D + c4);
  float4 p = *(const float4*)(pos + (size_t)t * D + c4);
  float4 r;
  r.x = a.x + p.x; r.y = a.y + p.y; r.z = a.z + p.z; r.w = a.w + p.w;
  *(float4*)(x + (size_t)n * D + c4) = r;
}

// one wave per row, D=512 -> 8 elems/lane; two-pass mean/var (matches ref)
__global__ __launch_bounds__(256) void ln_kernel(
    const float* __restrict__ x, const float* __restrict__ g,
    const float* __restrict__ b, float* __restrict__ out) {
  int lane = threadIdx.x & 63;
  int row = blockIdx.x * 4 + (threadIdx.x >> 6);
  const float* xr = x + (size_t)row * D;
  float vals[8];
  float s = 0.f;
#pragma unroll
  for (int i = 0; i < 8; ++i) { vals[i] = xr[lane + 64 * i]; s += vals[i]; }
  s = wave_sum(s);
  float mean = s * (1.f / D);
  float vs = 0.f;
#pragma unroll
  for (int i = 0; i < 8; ++i) { float d = vals[i] - mean; vs += d * d; }
  vs = wave_sum(vs);
  float rstd = 1.f / sqrtf(vs * (1.f / D) + 1e-5f);
  float* orow = out + (size_t)row * D;
#pragma unroll
  for (int i = 0; i < 8; ++i) {
    int c = lane + 64 * i;
    orow[c] = (vals[i] - mean) * rstd * g[c] + b[c];
  }
}

// C[M,N] = act(A[M,K] @ B[K,N] + bias + R); 64x64 tile, 16 k-step, 4x4 micro
template <bool RELU, bool BIAS, bool RES>
__global__ __launch_bounds__(256) void gemm_kernel(
    const float* __restrict__ A, const float* __restrict__ Bm,
    const float* __restrict__ bias, const float* __restrict__ R,
    float* __restrict__ C, int M, int N, int K) {
  __shared__ float As[16][72];   // [k][m], padded
  __shared__ float Bs[16][64];   // [k][n]
  const int tid = threadIdx.x;
  const int tx = tid & 15, ty = tid >> 4;
  const int m0 = blockIdx.y * 64, n0 = blockIdx.x * 64;
  const int lar = tid >> 2, lak = (tid & 3) << 2;
  const int lbk = tid >> 4, lbn = (tid & 15) << 2;
  const float* Aptr = A + (size_t)(m0 + lar) * K + lak;
  const float* Bptr = Bm + (size_t)lbk * N + n0 + lbn;
  float acc[4][4] = {};
  for (int k0 = 0; k0 < K; k0 += 16) {
    float4 av = *(const float4*)(Aptr + k0);
    float4 bv = *(const float4*)(Bptr + (size_t)k0 * N);
    __syncthreads();
    As[lak + 0][lar] = av.x; As[lak + 1][lar] = av.y;
    As[lak + 2][lar] = av.z; As[lak + 3][lar] = av.w;
    *(float4*)&Bs[lbk][lbn] = bv;
    __syncthreads();
#pragma unroll
    for (int kk = 0; kk < 16; ++kk) {
      float af[4], bf[4];
      *(float4*)af = *(const float4*)&As[kk][ty << 2];
      *(float4*)bf = *(const float4*)&Bs[kk][tx << 2];
#pragma unroll
      for (int i = 0; i < 4; ++i)
#pragma unroll
        for (int j = 0; j < 4; ++j)
          acc[i][j] = fmaf(af[i], bf[j], acc[i][j]);
    }
  }
#pragma unroll
  for (int i = 0; i < 4; ++i) {
    int m = m0 + (ty << 2) + i;
#pragma unroll
    for (int j = 0; j < 4; ++j) {
      int n = n0 + (tx << 2) + j;
      float val = acc[i][j];
      if (BIAS) val += bias[n];
      if (RES) val += R[(size_t)m * N + n];
      if (RELU) val = fmaxf(val, 0.f);
      C[(size_t)m * N + n] = val;
    }
  }
}

// flash attention: one wave per (b, head, query-row). lane = head-dim.
// q,k,v laid out [NTOK, D] with head h at cols h*64..h*64+63.
__global__ __launch_bounds__(256) void attn_kernel(
    const float* __restrict__ q, const float* __restrict__ k,
    const float* __restrict__ v, float* __restrict__ o) {
  const int lane = threadIdx.x & 63;
  const int wid = blockIdx.x * 4 + (threadIdx.x >> 6);  // [0, B*H*T)
  const int b = wid >> 14;            // H*T = 16384
  const int h = (wid >> 11) & (NH - 1);
  const int tq = wid & (TSEQ - 1);
  const size_t base = (size_t)b * TSEQ * D + (size_t)h * HD;
  const float scale = 0.04419417382415922f;  // 512^-0.5 (ref scales by D, not HD)
  float qi = q[base + (size_t)tq * D + lane] * scale;
  float m = -INFINITY, l = 0.f, oi = 0.f;
  for (int j0 = 0; j0 <= tq; j0 += 64) {
    int nk = min(64, tq - j0 + 1);
    float sj = -INFINITY;
    const float* kp = k + base + (size_t)j0 * D + lane;
    for (int j = 0; j < nk; ++j) {
      float s = wave_sum(qi * kp[(size_t)j * D]);
      if (lane == j) sj = s;
    }
    float mb = wave_max(sj);
    float mn = fmaxf(m, mb);
    float ef = __expf(m - mn);          // first iter: exp(-inf)=0
    float p = (sj == -INFINITY) ? 0.f : __expf(sj - mn);
    float ps = wave_sum(p);
    l = l * ef + ps;
    oi *= ef;
    const float* vp = v + base + (size_t)j0 * D + lane;
    for (int j = 0; j < nk; ++j) {
      float pj = __shfl(p, j, 64);
      oi = fmaf(pj, vp[(size_t)j * D], oi);
    }
    m = mn;
  }
  o[base + (size_t)tq * D + lane] = oi / l;
}

// per-row: row_loss[r] = logsumexp(logits[r,:]) - logits[r, tg[r]]
__global__ __launch_bounds__(256) void loss_row_kernel(
    const float* __restrict__ logits, const int* __restrict__ tg,
    float* __restrict__ row_loss) {
  const int row = blockIdx.x;
  const float4* lr = (const float4*)(logits + (size_t)row * VOCAB);
  const int n4 = VOCAB / 4;  // 8000
  __shared__ float red[4];
  float mx = -INFINITY;
  for (int i = threadIdx.x; i < n4; i += 256) {
    float4 t = lr[i];
    mx = fmaxf(fmaxf(fmaxf(mx, t.x), t.y), fmaxf(t.z, t.w));
  }
  mx = wave_max(mx);
  if ((threadIdx.x & 63) == 0) red[threadIdx.x >> 6] = mx;
  __syncthreads();
  mx = fmaxf(fmaxf(red[0], red[1]), fmaxf(red[2], red[3]));
  __syncthreads();
  float se = 0.f;
  for (int i = threadIdx.x; i < n4; i += 256) {
    float4 t = lr[i];
    se += __expf(t.x - mx) + __expf(t.y - mx) + __expf(t.z - mx) + __expf(t.w - mx);
  }
  se = wave_sum(se);
  if ((threadIdx.x & 63) == 0) red[threadIdx.x >> 6] = se;
  __syncthreads();
  if (threadIdx.x == 0) {
    float tot = red[0] + red[1] + red[2] + red[3];
    const float* l = logits + (size_t)row * VOCAB;
    row_loss[row] = mx + logf(tot) - l[tg[row]];
  }
}

__global__ __launch_bounds__(256) void loss_reduce_kernel(
    const float* __restrict__ rl, float* __restrict__ out) {
  float s = 0.f;
  for (int i = threadIdx.x; i < NTOK; i += 256) s += rl[i];
  __shared__ float red[4];
  s = wave_sum(s);
  if ((threadIdx.x & 63) == 0) red[threadIdx.x >> 6] = s;
  __syncthreads();
  if (threadIdx.x == 0)
    out[0] = (red[0] + red[1] + red[2] + red[3]) * (1.f / NTOK);
}

extern "C" void kernel_launch(void* const* d_in, const int* in_sizes, int n_in,
                              void* d_out, int out_size, void* d_ws, size_t ws_size,
                              hipStream_t stream) {
  const int* idx     = (const int*)d_in[0];
  const int* targets = (const int*)d_in[1];
  const float* tok_emb = (const float*)d_in[2];
  const float* pos_emb = (const float*)d_in[3];
  const float* Wq = (const float*)d_in[4];
  const float* Wk = (const float*)d_in[5];
  const float* Wv = (const float*)d_in[6];
  const float* Wo = (const float*)d_in[7];
  const float* bo = (const float*)d_in[8];
  const float* W1 = (const float*)d_in[9];
  const float* b1 = (const float*)d_in[10];
  const float* W2 = (const float*)d_in[11];
  const float* b2 = (const float*)d_in[12];
  const float* ln1_g = (const float*)d_in[13];
  const float* ln1_b = (const float*)d_in[14];
  const float* ln2_g = (const float*)d_in[15];
  const float* ln2_b = (const float*)d_in[16];
  const float* lnf_g = (const float*)d_in[17];
  const float* lnf_b = (const float*)d_in[18];
  const float* Whead = (const float*)d_in[19];
  const float* bhead = (const float*)d_in[20];
  float* out = (float*)d_out;

  // persistent scratch in d_ws: x, h, row_loss (~16.8 MB)
  float* ws = (float*)d_ws;
  float* x = ws;
  float* h = ws + (size_t)NTOK * D;
  float* row_loss = h + (size_t)NTOK * D;

  // transient scratch aliased into d_out (dead before head GEMM writes logits)
  float* q    = out;
  float* kbuf = out + 1 * (size_t)NTOK * D;
  float* vbuf = out + 2 * (size_t)NTOK * D;
  float* obuf = out + 3 * (size_t)NTOK * D;
  float* mlp  = out + 4 * (size_t)NTOK * D;  // NTOK*4D floats

  embed_kernel<<<NTOK * D / 4 / 256, 256, 0, stream>>>(idx, tok_emb, pos_emb, x);

  const dim3 g512(D / 64, NTOK / 64);
  const dim3 g2048(4 * D / 64, NTOK / 64);
  for (int l = 0; l < NLAYER; ++l) {
    ln_kernel<<<NTOK / 4, 256, 0, stream>>>(x, ln1_g + l * D, ln1_b + l * D, h);
    gemm_kernel<false, false, false><<<g512, 256, 0, stream>>>(
        h, Wq + (size_t)l * D * D, nullptr, nullptr, q, NTOK, D, D);
    gemm_kernel<false, false, false><<<g512, 256, 0, stream>>>(
        h, Wk + (size_t)l * D * D, nullptr, nullptr, kbuf, NTOK, D, D);
    gemm_kernel<false, false, false><<<g512, 256, 0, stream>>>(
        h, Wv + (size_t)l * D * D, nullptr, nullptr, vbuf, NTOK, D, D);
    attn_kernel<<<NTOK * NH / 4, 256, 0, stream>>>(q, kbuf, vbuf, obuf);
    gemm_kernel<false, true, true><<<g512, 256, 0, stream>>>(
        obuf, Wo + (size_t)l * D * D, bo + l * D, x, x, NTOK, D, D);
    ln_kernel<<<NTOK / 4, 256, 0, stream>>>(x, ln2_g + l * D, ln2_b + l * D, h);
    gemm_kernel<true, true, false><<<g2048, 256, 0, stream>>>(
        h, W1 + (size_t)l * D * 4 * D, b1 + l * 4 * D, nullptr, mlp, NTOK, 4 * D, D);
    gemm_kernel<false, true, true><<<g512, 256, 0, stream>>>(
        mlp, W2 + (size_t)l * 4 * D * D, b2 + l * D, x, x, NTOK, D, 4 * D);
  }
  ln_kernel<<<NTOK / 4, 256, 0, stream>>>(x, lnf_g, lnf_b, h);
  const dim3 ghead(VOCAB / 64, NTOK / 64);
  gemm_kernel<false, true, false><<<ghead, 256, 0, stream>>>(
      h, Whead, bhead, nullptr, out, NTOK, VOCAB, D);
  loss_row_kernel<<<NTOK, 256, 0, stream>>>(out, targets, row_loss);
  loss_reduce_kernel<<<1, 256, 0, stream>>>(row_loss, out + (size_t)NTOK * VOCAB);
}